// Round 5
// baseline (371.507 us; speedup 1.0000x reference)
//
#include <hip/hip_runtime.h>
#include <hip/hip_bf16.h>
#include <cstdint>

#define D_MODEL 256
#define NHEADS 8
#define DK 32
#define LDSPAD 4
#define LDSROW (D_MODEL + LDSPAD)   // 260 bf16 per LDS row; 520B = 130 dw == 2 mod 32 -> 2-way (free)
#define BM 64                       // rows per block tile

typedef float f32x4 __attribute__((ext_vector_type(4)));
typedef __bf16 bf16x8 __attribute__((ext_vector_type(8)));

__device__ __forceinline__ unsigned short f2bf_rne(float f) {
    unsigned int u = __float_as_uint(f);
    u += 0x7FFF + ((u >> 16) & 1);
    return (unsigned short)(u >> 16);
}
__device__ __forceinline__ float bf2f(unsigned short h) {
    return __uint_as_float(((unsigned int)h) << 16);
}

// ---------------- weight fp32 -> bf16 (MFMA B-fragment order) + edge histogram --
__global__ void conv_weights_hist(const float* __restrict__ W0, const float* __restrict__ W1,
                                  const float* __restrict__ W2, const float* __restrict__ W3,
                                  unsigned short* __restrict__ out,
                                  const int* __restrict__ dst, int E,
                                  int* __restrict__ counts) {
    int i = blockIdx.x * blockDim.x + threadIdx.x;
    if (i < 4 * 8192) {
        const int w    = i >> 13;
        const int rem  = i & 8191;            // (ntile*8 + kk)*64 + lane
        const int lane = rem & 63;
        const int kk   = (rem >> 6) & 7;
        const int ntile= rem >> 9;
        const int row  = ntile * 16 + (lane & 15);
        const int col  = kk * 32 + (lane >> 4) * 8;
        const float* Wsrc = (w == 0) ? W0 : (w == 1) ? W1 : (w == 2) ? W2 : W3;
        const float* sp = Wsrc + (size_t)row * D_MODEL + col;
        float4 x0 = *(const float4*)sp;
        float4 x1 = *(const float4*)(sp + 4);
        unsigned short* dp = out + (size_t)w * D_MODEL * D_MODEL + (size_t)rem * 8;
        ushort4 o0, o1;
        o0.x = f2bf_rne(x0.x); o0.y = f2bf_rne(x0.y); o0.z = f2bf_rne(x0.z); o0.w = f2bf_rne(x0.w);
        o1.x = f2bf_rne(x1.x); o1.y = f2bf_rne(x1.y); o1.z = f2bf_rne(x1.z); o1.w = f2bf_rne(x1.w);
        *(ushort4*)dp = o0;
        *(ushort4*)(dp + 4) = o1;
    } else {
        const int e = i - 4 * 8192;
        if (e < E) atomicAdd(&counts[dst[e]], 1);
    }
}

// ---------------- one-tile-per-block QKV GEMM ------------------------------------
// blockIdx.y selects q/k/v; blockIdx.x = 64-row m-tile. 512 threads = 8 waves;
// wave owns 2 n-tiles (32 cols) x 64 rows -> acc[4][2]. B-fragments (64 VGPR)
// re-fetched per block from L2 (W is 128KB/XCD-resident). No persistent loop:
// tile pipelining comes from block turnover; only 2 barriers per tile.
// Epilogue stores DIRECTLY from acc (no LDS transpose): per (mi,ni,r) the 16
// mrow-lanes cover 16 consecutive cols = 32B; ni pair completes 64B lines.
// kvbuf layout: node row = 512 halfwords = [K 0..255 | V 256..511].
__global__ __launch_bounds__(512, 4) void gemm_qkv(
    const float* __restrict__ Aq, const float* __restrict__ Ak, const float* __restrict__ Av,
    const unsigned short* __restrict__ Wsw,
    const float* __restrict__ bq, const float* __restrict__ bk, const float* __restrict__ bv,
    unsigned short* __restrict__ qbuf, unsigned short* __restrict__ kvbuf,
    int M)
{
    __shared__ __align__(16) unsigned short smem[BM * LDSROW];   // 33.3 KB

    const int which = blockIdx.y;
    const float* A = (which == 0) ? Aq : (which == 1) ? Ak : Av;
    const float* bias = (which == 0) ? bq : (which == 1) ? bk : bv;
    const unsigned short* Wb = Wsw + (size_t)which * D_MODEL * D_MODEL;
    unsigned short* outp = (which == 0) ? qbuf : kvbuf;
    const int out_stride = (which == 0) ? D_MODEL : 2 * D_MODEL;
    const int out_off    = (which == 2) ? D_MODEL : 0;

    const int lane  = threadIdx.x & 63;
    const int wave  = threadIdx.x >> 6;      // 0..7
    const int mrow  = lane & 15;
    const int quad  = lane >> 4;
    const int m0    = blockIdx.x * BM;

    // ---- B fragments: 2 n-tiles x 8 kk = 64 VGPRs ----
    bf16x8 bfr[2][8];
#pragma unroll
    for (int ni = 0; ni < 2; ++ni)
#pragma unroll
        for (int kk = 0; kk < 8; ++kk)
            bfr[ni][kk] = *(const bf16x8*)(Wb + ((size_t)((wave * 2 + ni) * 8 + kk) * 64 + lane) * 8);

    float bcol[2];
#pragma unroll
    for (int ni = 0; ni < 2; ++ni) bcol[ni] = bias[wave * 32 + ni * 16 + mrow];

    // ---- stage A tile (64 x 256 fp32 -> bf16 LDS); two halves to cap regs ----
#pragma unroll
    for (int half = 0; half < 2; ++half) {
        float4 x[4];
#pragma unroll
        for (int i = 0; i < 4; ++i) {
            const int g = (half * 4 + i) * 512 + threadIdx.x;   // float4 index 0..4095
            const int r = g >> 6, c4 = g & 63;
            const int grow = min(m0 + r, M - 1);
            x[i] = *(const float4*)(A + (size_t)grow * D_MODEL + c4 * 4);
        }
#pragma unroll
        for (int i = 0; i < 4; ++i) {
            const int g = (half * 4 + i) * 512 + threadIdx.x;
            const int r = g >> 6, c4 = g & 63;
            ushort4 o;
            o.x = f2bf_rne(x[i].x); o.y = f2bf_rne(x[i].y);
            o.z = f2bf_rne(x[i].z); o.w = f2bf_rne(x[i].w);
            *(ushort4*)(smem + r * LDSROW + c4 * 4) = o;
        }
    }
    __syncthreads();

    f32x4 acc[4][2] = {};
#pragma unroll
    for (int kk = 0; kk < 8; ++kk) {
        bf16x8 afr[4];
#pragma unroll
        for (int mi = 0; mi < 4; ++mi)
            afr[mi] = *(const bf16x8*)(smem + (mi * 16 + mrow) * LDSROW + kk * 32 + quad * 8);
#pragma unroll
        for (int mi = 0; mi < 4; ++mi)
#pragma unroll
            for (int ni = 0; ni < 2; ++ni)
                acc[mi][ni] = __builtin_amdgcn_mfma_f32_16x16x32_bf16(
                    afr[mi], bfr[ni][kk], acc[mi][ni], 0, 0, 0);
    }

    // ---- direct bf16 stores from acc ----
#pragma unroll
    for (int mi = 0; mi < 4; ++mi)
#pragma unroll
        for (int r = 0; r < 4; ++r) {
            const int row = m0 + mi * 16 + quad * 4 + r;
            if (row < M) {
#pragma unroll
                for (int ni = 0; ni < 2; ++ni)
                    outp[(size_t)row * out_stride + out_off + wave * 32 + ni * 16 + mrow] =
                        f2bf_rne(acc[mi][ni][r] + bcol[ni]);
            }
        }
}

// ---------------- one-tile-per-block output GEMM: out = attn(bf16) @ Wo^T + bo --
__global__ __launch_bounds__(512, 4) void gemm_out(
    const unsigned short* __restrict__ Ab, const unsigned short* __restrict__ Wb,
    const float* __restrict__ bias, float* __restrict__ outp, int M)
{
    __shared__ __align__(16) unsigned short smem[BM * LDSROW];   // 33.3 KB

    const int lane  = threadIdx.x & 63;
    const int wave  = threadIdx.x >> 6;
    const int mrow  = lane & 15;
    const int quad  = lane >> 4;
    const int m0    = blockIdx.x * BM;

    bf16x8 bfr[2][8];
#pragma unroll
    for (int ni = 0; ni < 2; ++ni)
#pragma unroll
        for (int kk = 0; kk < 8; ++kk)
            bfr[ni][kk] = *(const bf16x8*)(Wb + ((size_t)((wave * 2 + ni) * 8 + kk) * 64 + lane) * 8);

    float bcol[2];
#pragma unroll
    for (int ni = 0; ni < 2; ++ni) bcol[ni] = bias[wave * 32 + ni * 16 + mrow];

    // ---- stage A tile (64 x 256 bf16) into LDS ----
#pragma unroll
    for (int i = 0; i < 4; ++i) {
        const int g = i * 512 + threadIdx.x;     // ushort8 index 0..2047
        const int r = g >> 5, c8 = g & 31;
        const int grow = min(m0 + r, M - 1);
        bf16x8 x = *(const bf16x8*)(Ab + (size_t)grow * D_MODEL + c8 * 8);
        *(bf16x8*)(smem + r * LDSROW + c8 * 8) = x;
    }
    __syncthreads();

    f32x4 acc[4][2] = {};
#pragma unroll
    for (int kk = 0; kk < 8; ++kk) {
        bf16x8 afr[4];
#pragma unroll
        for (int mi = 0; mi < 4; ++mi)
            afr[mi] = *(const bf16x8*)(smem + (mi * 16 + mrow) * LDSROW + kk * 32 + quad * 8);
#pragma unroll
        for (int mi = 0; mi < 4; ++mi)
#pragma unroll
            for (int ni = 0; ni < 2; ++ni)
                acc[mi][ni] = __builtin_amdgcn_mfma_f32_16x16x32_bf16(
                    afr[mi], bfr[ni][kk], acc[mi][ni], 0, 0, 0);
    }

    // ---- direct fp32 stores from acc: 16 lanes x 4B = full 64B line per instr ----
#pragma unroll
    for (int mi = 0; mi < 4; ++mi)
#pragma unroll
        for (int r = 0; r < 4; ++r) {
            const int row = m0 + mi * 16 + quad * 4 + r;
            if (row < M) {
#pragma unroll
                for (int ni = 0; ni < 2; ++ni)
                    outp[(size_t)row * D_MODEL + wave * 32 + ni * 16 + mrow] =
                        acc[mi][ni][r] + bcol[ni];
            }
        }
}

// ---------------- CSR construction ----------------
__global__ void block_reduce_kernel(const int* __restrict__ counts, int N,
                                    int* __restrict__ blockSums) {
    const int g = blockIdx.x * 256 + threadIdx.x;
    int v = (g < N) ? counts[g] : 0;
#pragma unroll
    for (int d = 1; d < 64; d <<= 1) v += __shfl_xor(v, d);
    __shared__ int ws[4];
    if ((threadIdx.x & 63) == 0) ws[threadIdx.x >> 6] = v;
    __syncthreads();
    if (threadIdx.x == 0) blockSums[blockIdx.x] = ws[0] + ws[1] + ws[2] + ws[3];
}

__global__ void scan_blocks_kernel(int* __restrict__ blockSums, int G) {
    __shared__ int sh[256];
    const int t = threadIdx.x;
    int v = (t < G) ? blockSums[t] : 0;
    sh[t] = v;
    __syncthreads();
#pragma unroll
    for (int off = 1; off < 256; off <<= 1) {
        int add = (t >= off) ? sh[t - off] : 0;
        __syncthreads();
        sh[t] += add;
        __syncthreads();
    }
    if (t < G) blockSums[t] = sh[t] - v;   // exclusive
}

__global__ void scan_write_kernel(const int* __restrict__ counts, int N,
                                  const int* __restrict__ blockOffsets,
                                  int* __restrict__ offsets) {
    const int g = blockIdx.x * 256 + threadIdx.x;
    const int t = threadIdx.x;
    int v = (g < N) ? counts[g] : 0;
    __shared__ int sh[256];
    sh[t] = v;
    __syncthreads();
#pragma unroll
    for (int off = 1; off < 256; off <<= 1) {
        int add = (t >= off) ? sh[t - off] : 0;
        __syncthreads();
        sh[t] += add;
        __syncthreads();
    }
    if (g <= N) offsets[g] = sh[t] - v + blockOffsets[blockIdx.x];
}

__global__ void fill_kernel(const int* __restrict__ dst, const int* __restrict__ src, int E,
                            const int* __restrict__ offsets, int* __restrict__ cursor,
                            int* __restrict__ ssrc) {
    int i = blockIdx.x * blockDim.x + threadIdx.x;
    if (i < E) {
        int d = dst[i];
        int r = atomicAdd(&cursor[d], 1);
        ssrc[offsets[d] + r] = src[i];
    }
}

// ---------------- per-node online-softmax attention ----------------
// One wave per node. Lane l owns elements 4l..4l+3 (head = l>>3).
// kv layout: node row = 512 halfwords = [K 0..255 | V 256..511]; lane reads
// K at 4l (8B) and V at 256+4l (8B) -- both fully coalesced per wave.
__global__ __launch_bounds__(256) void attn_kernel(
    const unsigned short* __restrict__ qb, const unsigned short* __restrict__ kv,
    const int* __restrict__ offsets, const int* __restrict__ ssrc,
    unsigned short* __restrict__ attn, int N)
{
    const int node = blockIdx.x * 4 + (threadIdx.x >> 6);
    if (node >= N) return;
    const int lane = threadIdx.x & 63;

    ushort4 qu = *(const ushort4*)(qb + (size_t)node * D_MODEL + 4 * lane);
    const float sc = 0.17677669529663689f;  // 1/sqrt(32)
    float qx = bf2f(qu.x) * sc, qy = bf2f(qu.y) * sc,
          qz = bf2f(qu.z) * sc, qw = bf2f(qu.w) * sc;

    float m = -INFINITY, l = 0.f;
    float ax = 0.f, ay = 0.f, az = 0.f, aw = 0.f;

    const int e0 = offsets[node], e1 = offsets[node + 1];
    int e = e0;

    // ---- 8-edge stage: 16 independent 8B gathers in flight ----
    for (; e + 7 < e1; e += 8) {
        const unsigned short* b0 = kv + (size_t)ssrc[e]     * 512 + 4 * lane;
        const unsigned short* b1 = kv + (size_t)ssrc[e + 1] * 512 + 4 * lane;
        const unsigned short* b2 = kv + (size_t)ssrc[e + 2] * 512 + 4 * lane;
        const unsigned short* b3 = kv + (size_t)ssrc[e + 3] * 512 + 4 * lane;
        const unsigned short* b4 = kv + (size_t)ssrc[e + 4] * 512 + 4 * lane;
        const unsigned short* b5 = kv + (size_t)ssrc[e + 5] * 512 + 4 * lane;
        const unsigned short* b6 = kv + (size_t)ssrc[e + 6] * 512 + 4 * lane;
        const unsigned short* b7 = kv + (size_t)ssrc[e + 7] * 512 + 4 * lane;
        ushort4 k0 = *(const ushort4*)b0, v0 = *(const ushort4*)(b0 + D_MODEL);
        ushort4 k1 = *(const ushort4*)b1, v1 = *(const ushort4*)(b1 + D_MODEL);
        ushort4 k2 = *(const ushort4*)b2, v2 = *(const ushort4*)(b2 + D_MODEL);
        ushort4 k3 = *(const ushort4*)b3, v3 = *(const ushort4*)(b3 + D_MODEL);
        ushort4 k4 = *(const ushort4*)b4, v4 = *(const ushort4*)(b4 + D_MODEL);
        ushort4 k5 = *(const ushort4*)b5, v5 = *(const ushort4*)(b5 + D_MODEL);
        ushort4 k6 = *(const ushort4*)b6, v6 = *(const ushort4*)(b6 + D_MODEL);
        ushort4 k7 = *(const ushort4*)b7, v7 = *(const ushort4*)(b7 + D_MODEL);

        float p0 = qx * bf2f(k0.x) + qy * bf2f(k0.y) + qz * bf2f(k0.z) + qw * bf2f(k0.w);
        float p1 = qx * bf2f(k1.x) + qy * bf2f(k1.y) + qz * bf2f(k1.z) + qw * bf2f(k1.w);
        float p2 = qx * bf2f(k2.x) + qy * bf2f(k2.y) + qz * bf2f(k2.z) + qw * bf2f(k2.w);
        float p3 = qx * bf2f(k3.x) + qy * bf2f(k3.y) + qz * bf2f(k3.z) + qw * bf2f(k3.w);
        float p4 = qx * bf2f(k4.x) + qy * bf2f(k4.y) + qz * bf2f(k4.z) + qw * bf2f(k4.w);
        float p5 = qx * bf2f(k5.x) + qy * bf2f(k5.y) + qz * bf2f(k5.z) + qw * bf2f(k5.w);
        float p6 = qx * bf2f(k6.x) + qy * bf2f(k6.y) + qz * bf2f(k6.z) + qw * bf2f(k6.w);
        float p7 = qx * bf2f(k7.x) + qy * bf2f(k7.y) + qz * bf2f(k7.z) + qw * bf2f(k7.w);
#pragma unroll
        for (int d = 1; d <= 4; d <<= 1) {
            p0 += __shfl_xor(p0, d); p1 += __shfl_xor(p1, d);
            p2 += __shfl_xor(p2, d); p3 += __shfl_xor(p3, d);
            p4 += __shfl_xor(p4, d); p5 += __shfl_xor(p5, d);
            p6 += __shfl_xor(p6, d); p7 += __shfl_xor(p7, d);
        }
        float mnew = fmaxf(fmaxf(fmaxf(fmaxf(m, p0), fmaxf(p1, p2)), fmaxf(fmaxf(p3, p4), fmaxf(p5, p6))), p7);
        float alpha = __expf(m - mnew);
        float w0 = __expf(p0 - mnew), w1 = __expf(p1 - mnew);
        float w2 = __expf(p2 - mnew), w3 = __expf(p3 - mnew);
        float w4 = __expf(p4 - mnew), w5 = __expf(p5 - mnew);
        float w6 = __expf(p6 - mnew), w7 = __expf(p7 - mnew);
        ax = ax * alpha + w0 * bf2f(v0.x) + w1 * bf2f(v1.x) + w2 * bf2f(v2.x) + w3 * bf2f(v3.x)
                        + w4 * bf2f(v4.x) + w5 * bf2f(v5.x) + w6 * bf2f(v6.x) + w7 * bf2f(v7.x);
        ay = ay * alpha + w0 * bf2f(v0.y) + w1 * bf2f(v1.y) + w2 * bf2f(v2.y) + w3 * bf2f(v3.y)
                        + w4 * bf2f(v4.y) + w5 * bf2f(v5.y) + w6 * bf2f(v6.y) + w7 * bf2f(v7.y);
        az = az * alpha + w0 * bf2f(v0.z) + w1 * bf2f(v1.z) + w2 * bf2f(v2.z) + w3 * bf2f(v3.z)
                        + w4 * bf2f(v4.z) + w5 * bf2f(v5.z) + w6 * bf2f(v6.z) + w7 * bf2f(v7.z);
        aw = aw * alpha + w0 * bf2f(v0.w) + w1 * bf2f(v1.w) + w2 * bf2f(v2.w) + w3 * bf2f(v3.w)
                        + w4 * bf2f(v4.w) + w5 * bf2f(v5.w) + w6 * bf2f(v6.w) + w7 * bf2f(v7.w);
        l = l * alpha + w0 + w1 + w2 + w3 + w4 + w5 + w6 + w7;
        m = mnew;
    }

    // ---- 4-edge stage ----
    for (; e + 3 < e1; e += 4) {
        const unsigned short* b0 = kv + (size_t)ssrc[e]     * 512 + 4 * lane;
        const unsigned short* b1 = kv + (size_t)ssrc[e + 1] * 512 + 4 * lane;
        const unsigned short* b2 = kv + (size_t)ssrc[e + 2] * 512 + 4 * lane;
        const unsigned short* b3 = kv + (size_t)ssrc[e + 3] * 512 + 4 * lane;
        ushort4 k0 = *(const ushort4*)b0, v0 = *(const ushort4*)(b0 + D_MODEL);
        ushort4 k1 = *(const ushort4*)b1, v1 = *(const ushort4*)(b1 + D_MODEL);
        ushort4 k2 = *(const ushort4*)b2, v2 = *(const ushort4*)(b2 + D_MODEL);
        ushort4 k3 = *(const ushort4*)b3, v3 = *(const ushort4*)(b3 + D_MODEL);

        float p0 = qx * bf2f(k0.x) + qy * bf2f(k0.y) + qz * bf2f(k0.z) + qw * bf2f(k0.w);
        float p1 = qx * bf2f(k1.x) + qy * bf2f(k1.y) + qz * bf2f(k1.z) + qw * bf2f(k1.w);
        float p2 = qx * bf2f(k2.x) + qy * bf2f(k2.y) + qz * bf2f(k2.z) + qw * bf2f(k2.w);
        float p3 = qx * bf2f(k3.x) + qy * bf2f(k3.y) + qz * bf2f(k3.z) + qw * bf2f(k3.w);
#pragma unroll
        for (int d = 1; d <= 4; d <<= 1) {
            p0 += __shfl_xor(p0, d); p1 += __shfl_xor(p1, d);
            p2 += __shfl_xor(p2, d); p3 += __shfl_xor(p3, d);
        }
        float mnew = fmaxf(fmaxf(fmaxf(m, p0), fmaxf(p1, p2)), p3);
        float alpha = __expf(m - mnew);
        float w0 = __expf(p0 - mnew), w1 = __expf(p1 - mnew);
        float w2 = __expf(p2 - mnew), w3 = __expf(p3 - mnew);
        ax = ax * alpha + w0 * bf2f(v0.x) + w1 * bf2f(v1.x) + w2 * bf2f(v2.x) + w3 * bf2f(v3.x);
        ay = ay * alpha + w0 * bf2f(v0.y) + w1 * bf2f(v1.y) + w2 * bf2f(v2.y) + w3 * bf2f(v3.y);
        az = az * alpha + w0 * bf2f(v0.z) + w1 * bf2f(v1.z) + w2 * bf2f(v2.z) + w3 * bf2f(v3.z);
        aw = aw * alpha + w0 * bf2f(v0.w) + w1 * bf2f(v1.w) + w2 * bf2f(v2.w) + w3 * bf2f(v3.w);
        l = l * alpha + w0 + w1 + w2 + w3;
        m = mnew;
    }

    // ---- scalar tail ----
    for (; e < e1; ++e) {
        const unsigned short* b = kv + (size_t)ssrc[e] * 512 + 4 * lane;
        ushort4 ku = *(const ushort4*)b;
        ushort4 vu = *(const ushort4*)(b + D_MODEL);
        float p = qx * bf2f(ku.x) + qy * bf2f(ku.y) + qz * bf2f(ku.z) + qw * bf2f(ku.w);
        p += __shfl_xor(p, 1);
        p += __shfl_xor(p, 2);
        p += __shfl_xor(p, 4);
        float mnew  = fmaxf(m, p);
        float alpha = __expf(m - mnew);
        float w     = __expf(p - mnew);
        ax = ax * alpha + w * bf2f(vu.x);
        ay = ay * alpha + w * bf2f(vu.y);
        az = az * alpha + w * bf2f(vu.z);
        aw = aw * alpha + w * bf2f(vu.w);
        l = l * alpha + w;
        m = mnew;
    }

    const float inv = (l > 0.f) ? 1.f / l : 0.f;  // deg-0 nodes -> zeros
    ushort4 o;
    o.x = f2bf_rne(ax * inv);
    o.y = f2bf_rne(ay * inv);
    o.z = f2bf_rne(az * inv);
    o.w = f2bf_rne(aw * inv);
    *(ushort4*)(attn + (size_t)node * D_MODEL + 4 * lane) = o;
}

// ---------------- launch ----------------
extern "C" void kernel_launch(void* const* d_in, const int* in_sizes, int n_in,
                              void* d_out, int out_size, void* d_ws, size_t ws_size,
                              hipStream_t stream)
{
    const float* query = (const float*)d_in[0];
    const float* key   = (const float*)d_in[1];
    const float* value = (const float*)d_in[2];
    const int*   edges = (const int*)d_in[3];
    const float* Wq = (const float*)d_in[4];
    const float* bq = (const float*)d_in[5];
    const float* Wk = (const float*)d_in[6];
    const float* bk = (const float*)d_in[7];
    const float* Wv = (const float*)d_in[8];
    const float* bv = (const float*)d_in[9];
    const float* Wo = (const float*)d_in[10];
    const float* bo = (const float*)d_in[11];
    float* out = (float*)d_out;

    const int N = in_sizes[0] / D_MODEL;
    const int E = in_sizes[3] / 2;
    const int* dst = edges;
    const int* src = edges + E;

    char* ws = (char*)d_ws;
    size_t off = 0;
    auto alloc = [&](size_t bytes) {
        void* p = ws + off;
        off += (bytes + 255) & ~(size_t)255;
        return p;
    };
    unsigned short* qbuf  = (unsigned short*)alloc((size_t)N * D_MODEL * 2);
    unsigned short* kvbuf = (unsigned short*)alloc((size_t)N * 2 * D_MODEL * 2); // [K|V] flat
    unsigned short* attnb = (unsigned short*)alloc((size_t)N * D_MODEL * 2);
    unsigned short* Wbuf  = (unsigned short*)alloc((size_t)4 * D_MODEL * D_MODEL * 2);
    int*            counts  = (int*)alloc((size_t)2 * N * 4);   // counts + cursor contiguous
    int*            offsets = (int*)alloc((size_t)(N + 1) * 4);
    int*            ssrc    = (int*)alloc((size_t)E * 4);
    int*            bsums   = (int*)alloc((size_t)256 * 4);

    hipMemsetAsync(counts, 0, (size_t)2 * N * 4, stream);

    const int fused_threads = 4 * 8192 + E;
    conv_weights_hist<<<(fused_threads + 255) / 256, 256, 0, stream>>>(
        Wq, Wk, Wv, Wo, Wbuf, dst, E, counts);

    const int mtiles = (N + BM - 1) / BM;    // 782
    gemm_qkv<<<dim3(mtiles, 3), 512, 0, stream>>>(query, key, value, Wbuf,
                                                  bq, bk, bv, qbuf, kvbuf, N);

    const int G = (N + 256) / 256;  // ceil((N+1)/256)
    block_reduce_kernel<<<G, 256, 0, stream>>>(counts, N, bsums);
    scan_blocks_kernel<<<1, 256, 0, stream>>>(bsums, G);
    scan_write_kernel<<<G, 256, 0, stream>>>(counts, N, bsums, offsets);

    const int eblocks = (E + 255) / 256;
    fill_kernel<<<eblocks, 256, 0, stream>>>(dst, src, E, offsets, counts + N, ssrc);
    attn_kernel<<<(N + 3) / 4, 256, 0, stream>>>(qbuf, kvbuf, offsets, ssrc, attnb, N);

    gemm_out<<<mtiles, 512, 0, stream>>>(attnb, Wbuf + 3 * D_MODEL * D_MODEL, bo, out, N);
}